// Round 2
// baseline (328.848 us; speedup 1.0000x reference)
//
#include <hip/hip_runtime.h>

// AFM layer, MI355X gfx950.
// out[b] = sum_p attn_p * s_p,  s_p = sum_d x[i,d]x[j,d]p[d]
// R7: latency-bound -> raise TLP: TWO waves per batch share one LDS X-copy,
// split 25 bodies 12/13; partials combined via tiny LDS reduce.
// R8: intra-wave software pipeline. rocprof showed VALUBusy 56%,
// MfmaUtil 18%, occupancy 37%, LDS conflicts 0, HBM 8% -> latency-bound on the
// body's serial MFMA-chain -> logit dependency (~130cyc of MFMA latency with
// only ~32cyc of independent sp-dots to hide it). Split body into
//   phase1: ds_read xj, prod (pk_mul), sp fdot2 trees, issue 4 chained MFMA
//   phase2: cvt/relu/fdot2 logit from C, shfl, exp2, accumulate
// and defer phase2 by ONE body (A/B ping-pong, no frag copies). Body t+1's
// phase1 + body t's phase2 now fill the MFMA shadow. Carried state per slot:
// C-frag (16 VGPR) + sp + valid. Est. ~110 VGPR < 128 cap of (256,4); R6's
// spill disaster was 2 FULL streams (2x everything), this is 1-deep phase skew.
// R9: resubmit of R8 verbatim — R8 bench aborted on container acquisition
// (infra flake, no kernel signal).
// LDS: R2's padded stride-76 rows, b64 accesses — MEASURED 0 bank conflicts.
// Pair schedule per batch (25 bodies, 780/800 slots):
//   t=1..15 : 32-rotation (nl,(nl+t)&31) all-valid (prod symmetric);
//   t=16    : half-rotation, nl<16;  t=17..24: uniform rows 32..39;
//   cleanup : 8-triangle of fields 32..39 (28 pairs, closed-form unrank).
// Role 0: t=1..12. Role 1: t=13..24 + cleanup.
// __launch_bounds__(256,4): (256,8) strangles allocator -> spill (R3).

typedef _Float16 f16;
typedef f16 f16x2 __attribute__((ext_vector_type(2)));
typedef f16 f16x4 __attribute__((ext_vector_type(4)));
typedef f16 f16x8 __attribute__((ext_vector_type(8)));
typedef float fx16 __attribute__((ext_vector_type(16)));

#define NF 40
#define NB 8192
#define STR 76   // f16 elements per LDS row (152 B) — conflict-free (R2)

union V8 { f16x8 v8; f16x4 v4[2]; f16x2 v2[4]; };

__global__ __launch_bounds__(256, 4) void afm_kernel(
    const float* __restrict__ x,   // [8192,40,64]
    const float* __restrict__ W1,  // [64,32]
    const float* __restrict__ b1,  // [32]
    const float* __restrict__ w2,  // [32]
    const float* __restrict__ p,   // [64]
    float* __restrict__ out)       // [8192]
{
    __shared__ f16 xh[2][NF * STR];     // 2 batches x 40 x 76 f16 = 12,160 B
    __shared__ float red[2][2][2];      // [batch][role][aW,aS]

    const int tid  = threadIdx.x;
    const int wid  = tid >> 6;
    const int lane = tid & 63;
    const int bl   = wid >> 1;          // batch-local 0/1
    const int role = wid & 1;           // 0: t=1..12, 1: t=13..24 + cleanup
    const int b0   = blockIdx.x * 2;

    f16* Xs = &xh[bl][0];

    // ---- stage 2 batches (5120 floats) -> LDS f16, stride-76 rows ----
    const float4* xb = (const float4*)(x + (size_t)b0 * (NF * 64));
#pragma unroll
    for (int t = 0; t < 3; ++t) {
        int g = t * 256 + tid;                 // granule 0..639 (8 f16 each)
        if (g < 640) {
            float4 v0 = xb[g * 2];
            float4 v1 = xb[g * 2 + 1];
            f16x4 lo = { (f16)v0.x, (f16)v0.y, (f16)v0.z, (f16)v0.w };
            f16x4 hi = { (f16)v1.x, (f16)v1.y, (f16)v1.z, (f16)v1.w };
            int bsel = (g >= 320);
            int gi = g - (bsel ? 320 : 0);
            int row = gi >> 3, gg = gi & 7;
            f16* dst = &xh[bsel][0] + row * STR + gg * 8;
            *(f16x4*)dst = lo;                 // 8B-aligned b64 writes
            *(f16x4*)(dst + 4) = hi;
        }
    }
    __syncthreads();

    const int nl = lane & 31;   // MFMA column / field index base
    const int hh = lane >> 5;   // wave half -> k sub-block + a-row group
    const int h8 = hh * 8;

    // ---- A-frags: W1^T, A[m=a][k=h8+j], d = kt*16 + h8 + j ----
    f16x8 w1f[4];
#pragma unroll
    for (int kt = 0; kt < 4; ++kt)
#pragma unroll
        for (int j = 0; j < 8; ++j)
            w1f[kt][j] = (f16)W1[(kt * 16 + h8 + j) * 32 + nl];

    // ---- p packed to match prod-frag element order (for fdot2) ----
    f16x2 pp[16];
#pragma unroll
    for (int kt = 0; kt < 4; ++kt)
#pragma unroll
        for (int m = 0; m < 4; ++m) {
            f16x2 t2 = { (f16)p[kt * 16 + h8 + 2 * m], (f16)p[kt * 16 + h8 + 2 * m + 1] };
            pp[kt * 4 + m] = t2;
        }

    // ---- b1 as persistent C-frag; w2*log2e packed f16 (exp2 direct) ----
    fx16 b1C;
    f16x2 w2h[8];
#pragma unroll
    for (int r = 0; r < 16; ++r) {
        int a = (r & 3) + 8 * (r >> 2) + 4 * hh;
        b1C[r] = b1[a];
    }
#pragma unroll
    for (int m = 0; m < 8; ++m) {
        int r = 2 * m;
        int a = (r & 3) + 8 * (r >> 2) + 4 * hh;
        f16x2 t2 = { (f16)(w2[a] * 1.44269504f), (f16)(w2[a + 1] * 1.44269504f) };
        w2h[m] = t2;
    }

    // ---- xi frags for row nl ----
    f16x4 xif[8];
    {
        const f16* src = Xs + nl * STR + h8;
#pragma unroll
        for (int kt = 0; kt < 4; ++kt) {
            xif[2 * kt]     = *(const f16x4*)(src + kt * 16);
            xif[2 * kt + 1] = *(const f16x4*)(src + kt * 16 + 4);
        }
    }

    float accW = 0.f, accWS = 0.f;

    // phase1: read xj, prod, sp-dots, ISSUE the 4-chain MFMA. C not consumed.
    auto phase1 = [&](const f16x4* xi, int jrow, fx16& Cout, float& spOut) {
        const f16* base = Xs + jrow * STR + h8;
        V8 pr[4];
#pragma unroll
        for (int kt = 0; kt < 4; ++kt) {
            f16x4 a0 = *(const f16x4*)(base + kt * 16);       // ds_read_b64
            f16x4 a1 = *(const f16x4*)(base + kt * 16 + 4);
            pr[kt].v4[0] = xi[2 * kt] * a0;                    // v_pk_mul_f16
            pr[kt].v4[1] = xi[2 * kt + 1] * a1;
        }
        // h = W1^T prod + b1 : chain C from persistent b1 frag
        fx16 C = __builtin_amdgcn_mfma_f32_32x32x16_f16(w1f[0], pr[0].v8, b1C, 0, 0, 0);
        C = __builtin_amdgcn_mfma_f32_32x32x16_f16(w1f[1], pr[1].v8, C, 0, 0, 0);
        C = __builtin_amdgcn_mfma_f32_32x32x16_f16(w1f[2], pr[2].v8, C, 0, 0, 0);
        C = __builtin_amdgcn_mfma_f32_32x32x16_f16(w1f[3], pr[3].v8, C, 0, 0, 0);
        // s_p partial: 4 parallel fdot2 trees (chain depth 4) — independent of C
        float s0 = 0.f, s1 = 0.f, s2 = 0.f, s3 = 0.f;
#pragma unroll
        for (int m = 0; m < 4; ++m) {
            s0 = __builtin_amdgcn_fdot2(pr[0].v2[m], pp[m],      s0, false);
            s1 = __builtin_amdgcn_fdot2(pr[1].v2[m], pp[4 + m],  s1, false);
            s2 = __builtin_amdgcn_fdot2(pr[2].v2[m], pp[8 + m],  s2, false);
            s3 = __builtin_amdgcn_fdot2(pr[3].v2[m], pp[12 + m], s3, false);
        }
        float sp = (s0 + s1) + (s2 + s3);
        sp += __shfl_xor(sp, 32);   // combine k-halves (off C critical path)
        Cout = C;
        spOut = sp;
    };

    // phase2: consume C (one body later — MFMA latency already elapsed)
    auto phase2 = [&](const fx16& C, float sp, bool valid) {
        const f16x2 z2 = { (f16)0.f, (f16)0.f };
        float l0 = 0.f, l1 = 0.f;
#pragma unroll
        for (int m = 0; m < 8; ++m) {
            f16x2 hm = __builtin_bit_cast(f16x2,
                __builtin_amdgcn_cvt_pkrtz(C[2 * m], C[2 * m + 1]));
            hm = __builtin_elementwise_max(hm, z2);            // v_pk_max_f16
            if (m & 1) l1 = __builtin_amdgcn_fdot2(hm, w2h[m], l1, false);
            else       l0 = __builtin_amdgcn_fdot2(hm, w2h[m], l0, false);
        }
        float l = l0 + l1;
        l += __shfl_xor(l, 32);     // combine a-halves
        float w = __builtin_amdgcn_exp2f(l);   // max-free softmax (|l| small)
        if (!valid) w = 0.f;
        accW += w;
        accWS = fmaf(w, sp, accWS);
    };

    const int tb = 1 + role * 12;
    auto jrowf  = [&](int t) { return (t <= 16) ? ((nl + t) & 31) : (t + 15); };
    auto validf = [&](int t) { return (t != 16) || (nl < 16); };

    // ---- 1-deep pipelined schedule: A/B ping-pong, no frag copies ----
    fx16 CA, CB;
    float spA, spB;
    bool vA, vB;

    phase1(xif, jrowf(tb), CA, spA); vA = validf(tb);
#pragma unroll 1
    for (int k = 0; k < 5; ++k) {
        int t1 = tb + 1 + 2 * k;
        int t2 = tb + 2 + 2 * k;
        phase1(xif, jrowf(t1), CB, spB); vB = validf(t1);
        phase2(CA, spA, vA);
        phase1(xif, jrowf(t2), CA, spA); vA = validf(t2);
        phase2(CB, spB, vB);
    }
    {
        int tl = tb + 11;
        phase1(xif, jrowf(tl), CB, spB); vB = validf(tl);
        phase2(CA, spA, vA);
    }
    if (role) {   // cleanup: 28 pairs among fields 32..39 (lanes nl<28)
        int q = nl < 28 ? nl : 27;
        float disc = 225.0f - 8.0f * (float)q;
        int ii = (int)((15.0f - sqrtf(disc)) * 0.5f);
        if (ii * (15 - ii) / 2 > q) --ii;                 // sqrt 1-ulp fixups
        if ((ii + 1) * (14 - ii) / 2 <= q) ++ii;
        int jj = q - ii * (15 - ii) / 2 + ii + 1;
        int iC = 32 + ii, jC = 32 + jj;                   // pair (iC,jC), iC<jC
        f16x4 xi2[8];
        const f16* src = Xs + iC * STR + h8;
#pragma unroll
        for (int kt = 0; kt < 4; ++kt) {
            xi2[2 * kt]     = *(const f16x4*)(src + kt * 16);
            xi2[2 * kt + 1] = *(const f16x4*)(src + kt * 16 + 4);
        }
        phase1(xi2, jC, CA, spA); vA = (nl < 28);
        phase2(CB, spB, vB);
        phase2(CA, spA, vA);
    } else {
        phase2(CB, spB, vB);
    }

    // reduce across the 32 columns (halves already identical)
#pragma unroll
    for (int m = 16; m >= 1; m >>= 1) {
        accW  += __shfl_xor(accW, m);
        accWS += __shfl_xor(accWS, m);
    }
    if (lane == 0) {
        red[bl][role][0] = accW;
        red[bl][role][1] = accWS;
    }
    __syncthreads();
    if (tid < 2) {
        float W = red[tid][0][0] + red[tid][1][0];
        float S = red[tid][0][1] + red[tid][1][1];
        out[b0 + tid] = S / W;
    }
}

extern "C" void kernel_launch(void* const* d_in, const int* in_sizes, int n_in,
                              void* d_out, int out_size, void* d_ws, size_t ws_size,
                              hipStream_t stream) {
    const float* x  = (const float*)d_in[0];
    const float* W1 = (const float*)d_in[1];
    const float* b1 = (const float*)d_in[2];
    const float* w2 = (const float*)d_in[3];
    const float* p  = (const float*)d_in[4];
    float* out = (float*)d_out;
    dim3 grid(NB / 2), block(256);
    hipLaunchKernelGGL(afm_kernel, grid, block, 0, stream, x, W1, b1, w2, p, out);
}

// Round 3
// 164.318 us; speedup vs baseline: 2.0013x; 2.0013x over previous
//
#include <hip/hip_runtime.h>

// AFM layer, MI355X gfx950.
// out[b] = sum_p attn_p * s_p,  s_p = sum_d x[i,d]x[j,d]p[d]
// R7: latency-bound -> raise TLP: TWO waves per batch share one LDS X-copy,
// split 25 bodies 12/13; partials combined via tiny LDS reduce. 62us/dispatch,
// VALUBusy 56%, MfmaUtil 18%, occupancy 37%, 0 bank conflicts, no spill.
// R8/R9 FAILED: 1-deep ping-pong pipeline (phase1/phase2 lambdas with fx16&
// outputs + reg-array pointers) -> compiler demoted carried C-frags to
// scratch: FETCH 41->504MB, WRITE 0.1->221MB, 62->237us. Lesson: multi-site
// lambdas with reference outs / pointer-to-reg-array args are spill bait;
// keep the single-lambda loop-local-SSA structure that allocated 64 VGPR.
// R10 (this round): move sp off the VALU pipe onto the idle MFMA pipe.
// sp = sum_d prod*p is a K-reduction of the SAME B-operand (pr) the W1-MFMA
// consumes -> second chained MFMA with A2 = p in row 0 only (lanes nl==0),
// rows 1..31 zero. D2[0,n] = sp for pair n, lands in S[0] on hh=0 lanes;
// hh=1 gets row4 = 0 automatically, and the final 32-lane reduce only mixes
// lanes 0..31, so no masking/shfl needed. Deletes 16 fdot2 + 3 adds + 1 shfl
// per body (~30% of body VALU incl. a 4-deep dep chain) for 4 MFMA issues on
// a pipe at 18% util. pp regs (16) -> pA regs (16): net-zero persistent.
// LDS: R2's padded stride-76 rows, b64 accesses — MEASURED 0 bank conflicts.
// Pair schedule per batch (25 bodies, 780/800 slots):
//   t=1..15 : 32-rotation (nl,(nl+t)&31) all-valid (prod symmetric);
//   t=16    : half-rotation, nl<16;  t=17..24: uniform rows 32..39;
//   cleanup : 8-triangle of fields 32..39 (28 pairs, closed-form unrank).
// Role 0: t=1..12. Role 1: t=13..24 + cleanup.
// __launch_bounds__(256,4): (256,8) strangles allocator -> spill (R3).

typedef _Float16 f16;
typedef f16 f16x2 __attribute__((ext_vector_type(2)));
typedef f16 f16x4 __attribute__((ext_vector_type(4)));
typedef f16 f16x8 __attribute__((ext_vector_type(8)));
typedef float fx16 __attribute__((ext_vector_type(16)));

#define NF 40
#define NB 8192
#define STR 76   // f16 elements per LDS row (152 B) — conflict-free (R2)

union V8 { f16x8 v8; f16x4 v4[2]; f16x2 v2[4]; };

__global__ __launch_bounds__(256, 4) void afm_kernel(
    const float* __restrict__ x,   // [8192,40,64]
    const float* __restrict__ W1,  // [64,32]
    const float* __restrict__ b1,  // [32]
    const float* __restrict__ w2,  // [32]
    const float* __restrict__ p,   // [64]
    float* __restrict__ out)       // [8192]
{
    __shared__ f16 xh[2][NF * STR];     // 2 batches x 40 x 76 f16 = 12,160 B
    __shared__ float red[2][2][2];      // [batch][role][aW,aS]

    const int tid  = threadIdx.x;
    const int wid  = tid >> 6;
    const int lane = tid & 63;
    const int bl   = wid >> 1;          // batch-local 0/1
    const int role = wid & 1;           // 0: t=1..12, 1: t=13..24 + cleanup
    const int b0   = blockIdx.x * 2;

    f16* Xs = &xh[bl][0];

    // ---- stage 2 batches (5120 floats) -> LDS f16, stride-76 rows ----
    const float4* xb = (const float4*)(x + (size_t)b0 * (NF * 64));
#pragma unroll
    for (int t = 0; t < 3; ++t) {
        int g = t * 256 + tid;                 // granule 0..639 (8 f16 each)
        if (g < 640) {
            float4 v0 = xb[g * 2];
            float4 v1 = xb[g * 2 + 1];
            f16x4 lo = { (f16)v0.x, (f16)v0.y, (f16)v0.z, (f16)v0.w };
            f16x4 hi = { (f16)v1.x, (f16)v1.y, (f16)v1.z, (f16)v1.w };
            int bsel = (g >= 320);
            int gi = g - (bsel ? 320 : 0);
            int row = gi >> 3, gg = gi & 7;
            f16* dst = &xh[bsel][0] + row * STR + gg * 8;
            *(f16x4*)dst = lo;                 // 8B-aligned b64 writes
            *(f16x4*)(dst + 4) = hi;
        }
    }
    __syncthreads();

    const int nl = lane & 31;   // MFMA column / field index base
    const int hh = lane >> 5;   // wave half -> k sub-block + a-row group
    const int h8 = hh * 8;

    // ---- A-frags: W1^T, A[m=a][k=h8+j], d = kt*16 + h8 + j ----
    f16x8 w1f[4];
#pragma unroll
    for (int kt = 0; kt < 4; ++kt)
#pragma unroll
        for (int j = 0; j < 8; ++j)
            w1f[kt][j] = (f16)W1[(kt * 16 + h8 + j) * 32 + nl];

    // ---- A2-frags: p in row m=0 only (lanes nl==0), rows 1..31 zero ----
    // D2[0,n] = sum_k p[k] * prod[k,n] = sp for pair n (full k after 4-chain)
    f16x8 pA[4];
#pragma unroll
    for (int kt = 0; kt < 4; ++kt)
#pragma unroll
        for (int j = 0; j < 8; ++j)
            pA[kt][j] = (nl == 0) ? (f16)p[kt * 16 + h8 + j] : (f16)0.f;

    // ---- b1 as persistent C-frag; w2*log2e packed f16 (exp2 direct) ----
    fx16 b1C;
    f16x2 w2h[8];
#pragma unroll
    for (int r = 0; r < 16; ++r) {
        int a = (r & 3) + 8 * (r >> 2) + 4 * hh;
        b1C[r] = b1[a];
    }
#pragma unroll
    for (int m = 0; m < 8; ++m) {
        int r = 2 * m;
        int a = (r & 3) + 8 * (r >> 2) + 4 * hh;
        f16x2 t2 = { (f16)(w2[a] * 1.44269504f), (f16)(w2[a + 1] * 1.44269504f) };
        w2h[m] = t2;
    }

    fx16 zC;   // zero C-init for the sp chain
#pragma unroll
    for (int r = 0; r < 16; ++r) zC[r] = 0.f;

    // ---- xi frags for row nl ----
    f16x4 xif[8];
    {
        const f16* src = Xs + nl * STR + h8;
#pragma unroll
        for (int kt = 0; kt < 4; ++kt) {
            xif[2 * kt]     = *(const f16x4*)(src + kt * 16);
            xif[2 * kt + 1] = *(const f16x4*)(src + kt * 16 + 4);
        }
    }

    float accW = 0.f, accWS = 0.f;

    auto body = [&](const f16x4* xi, int jrow, bool valid) {
        const f16* base = Xs + jrow * STR + h8;
        V8 pr[4];
#pragma unroll
        for (int kt = 0; kt < 4; ++kt) {
            f16x4 a0 = *(const f16x4*)(base + kt * 16);       // ds_read_b64
            f16x4 a1 = *(const f16x4*)(base + kt * 16 + 4);
            pr[kt].v4[0] = xi[2 * kt] * a0;                    // v_pk_mul_f16
            pr[kt].v4[1] = xi[2 * kt + 1] * a1;
        }
        // Two independent chained MFMA streams over the same B-operand:
        //   C: h = W1^T prod + b1   (C-init = persistent b1 frag)
        //   S: sp = p . prod        (C-init = 0, A2 row0-only)
        fx16 C = __builtin_amdgcn_mfma_f32_32x32x16_f16(w1f[0], pr[0].v8, b1C, 0, 0, 0);
        fx16 S = __builtin_amdgcn_mfma_f32_32x32x16_f16(pA[0],  pr[0].v8, zC,  0, 0, 0);
        C = __builtin_amdgcn_mfma_f32_32x32x16_f16(w1f[1], pr[1].v8, C, 0, 0, 0);
        S = __builtin_amdgcn_mfma_f32_32x32x16_f16(pA[1],  pr[1].v8, S, 0, 0, 0);
        C = __builtin_amdgcn_mfma_f32_32x32x16_f16(w1f[2], pr[2].v8, C, 0, 0, 0);
        S = __builtin_amdgcn_mfma_f32_32x32x16_f16(pA[2],  pr[2].v8, S, 0, 0, 0);
        C = __builtin_amdgcn_mfma_f32_32x32x16_f16(w1f[3], pr[3].v8, C, 0, 0, 0);
        S = __builtin_amdgcn_mfma_f32_32x32x16_f16(pA[3],  pr[3].v8, S, 0, 0, 0);
        // sp: row 0 of D2 = S[0] on hh==0 lanes (hh==1 reads row 4 == 0;
        // harmless — final reduce only mixes lanes 0..31 and lane 0 writes)
        float sp = S[0];
        // logit partial: relu(h).(w2*log2e) in packed f16, 2 parallel trees
        const f16x2 z2 = { (f16)0.f, (f16)0.f };
        float l0 = 0.f, l1 = 0.f;
#pragma unroll
        for (int m = 0; m < 8; ++m) {
            f16x2 hm = __builtin_bit_cast(f16x2,
                __builtin_amdgcn_cvt_pkrtz(C[2 * m], C[2 * m + 1]));
            hm = __builtin_elementwise_max(hm, z2);            // v_pk_max_f16
            if (m & 1) l1 = __builtin_amdgcn_fdot2(hm, w2h[m], l1, false);
            else       l0 = __builtin_amdgcn_fdot2(hm, w2h[m], l0, false);
        }
        float l = l0 + l1;
        l += __shfl_xor(l, 32);     // combine a-halves
        float w = __builtin_amdgcn_exp2f(l);   // max-free softmax (|l| small)
        if (!valid) w = 0.f;
        accW += w;
        accWS = fmaf(w, sp, accWS);
    };

    // 12 (role 0) or 12+cleanup (role 1) bodies
    const int tb = 1 + role * 12;
    for (int t = tb; t < tb + 12; ++t) {
        int jrow = (t <= 16) ? ((nl + t) & 31) : (t + 15);
        bool valid = (t != 16) || (nl < 16);
        body(xif, jrow, valid);
    }
    if (role) {   // cleanup: 28 pairs among fields 32..39 (lanes nl<28)
        int q = nl < 28 ? nl : 27;
        float disc = 225.0f - 8.0f * (float)q;
        int ii = (int)((15.0f - sqrtf(disc)) * 0.5f);
        if (ii * (15 - ii) / 2 > q) --ii;                 // sqrt 1-ulp fixups
        if ((ii + 1) * (14 - ii) / 2 <= q) ++ii;
        int jj = q - ii * (15 - ii) / 2 + ii + 1;
        int iC = 32 + ii, jC = 32 + jj;                   // pair (iC,jC), iC<jC
        f16x4 xi2[8];
        const f16* src = Xs + iC * STR + h8;
#pragma unroll
        for (int kt = 0; kt < 4; ++kt) {
            xi2[2 * kt]     = *(const f16x4*)(src + kt * 16);
            xi2[2 * kt + 1] = *(const f16x4*)(src + kt * 16 + 4);
        }
        body(xi2, jC, nl < 28);
    }

    // reduce across the 32 columns (lane 0 only mixes lanes 0..31 = hh0)
#pragma unroll
    for (int m = 16; m >= 1; m >>= 1) {
        accW  += __shfl_xor(accW, m);
        accWS += __shfl_xor(accWS, m);
    }
    if (lane == 0) {
        red[bl][role][0] = accW;
        red[bl][role][1] = accWS;
    }
    __syncthreads();
    if (tid < 2) {
        float W = red[tid][0][0] + red[tid][1][0];
        float S = red[tid][0][1] + red[tid][1][1];
        out[b0 + tid] = S / W;
    }
}

extern "C" void kernel_launch(void* const* d_in, const int* in_sizes, int n_in,
                              void* d_out, int out_size, void* d_ws, size_t ws_size,
                              hipStream_t stream) {
    const float* x  = (const float*)d_in[0];
    const float* W1 = (const float*)d_in[1];
    const float* b1 = (const float*)d_in[2];
    const float* w2 = (const float*)d_in[3];
    const float* p  = (const float*)d_in[4];
    float* out = (float*)d_out;
    dim3 grid(NB / 2), block(256);
    hipLaunchKernelGGL(afm_kernel, grid, block, 0, stream, x, W1, b1, w2, p, out);
}